// Round 1
// baseline (166.488 us; speedup 1.0000x reference)
//
#include <hip/hip_runtime.h>
#include <hip/hip_bf16.h>

#define NPTS 768
#define SCALE 0.10206207261596575f  // 1/sqrt(96)

// ---------------- K1: Qx = channel_equi_vec_normalize(vn_linear_leaky(x, Wq_f, Wq_d)) ----------------
// block = 256 = 8 groups of 32 lanes; group handles one (b,n); lane = out-channel c.
__global__ __launch_bounds__(256) void k1_qx(const float* __restrict__ x,
    const float* __restrict__ Wf, const float* __restrict__ Wd, float* __restrict__ qx)
{
  __shared__ float2 w2[1024];     // [cin][c] packed (Wf, Wd)
  __shared__ float4 xs[8][32];    // per group: [cin] -> (x,y,z,pad)
  int tid = threadIdx.x;
  for (int i = tid; i < 1024; i += 256) {
    int cin = i >> 5, c = i & 31;
    w2[i] = make_float2(Wf[c * 32 + cin], Wd[c * 32 + cin]);
  }
  int g = tid >> 5, s = tid & 31;
  int p = blockIdx.x * 8 + g;
  int b = p / NPTS, n = p % NPTS;
  for (int t = s; t < 96; t += 32) {
    float v = x[(b * 96 + t) * NPTS + n];
    ((float*)&xs[g][t / 3])[t % 3] = v;
  }
  __syncthreads();
  int c = s;
  float pf0 = 0, pf1 = 0, pf2 = 0, pd0 = 0, pd1 = 0, pd2 = 0;
#pragma unroll
  for (int cin = 0; cin < 32; cin++) {
    float2 w = w2[(cin << 5) + c];
    float4 xv = xs[g][cin];
    pf0 = fmaf(w.x, xv.x, pf0); pf1 = fmaf(w.x, xv.y, pf1); pf2 = fmaf(w.x, xv.z, pf2);
    pd0 = fmaf(w.y, xv.x, pd0); pd1 = fmaf(w.y, xv.y, pd1); pd2 = fmaf(w.y, xv.z, pd2);
  }
  float dot = pf0 * pd0 + pf1 * pd1 + pf2 * pd2;
  float dsq = pd0 * pd0 + pd1 * pd1 + pd2 * pd2;
  float q0 = pf0, q1 = pf1, q2 = pf2;
  if (dot < 0.f) {
    float r = 0.8f * dot / (dsq + 1e-6f);
    q0 -= r * pd0; q1 -= r * pd1; q2 -= r * pd2;
  }
  float nrm = sqrtf(q0 * q0 + q1 * q1 + q2 * q2);
  float n2 = nrm * nrm;
#pragma unroll
  for (int m = 1; m <= 16; m <<= 1) n2 += __shfl_xor(n2, m);
  float ch = sqrtf(n2);
  float fac = (nrm / fmaxf(ch, 1e-12f)) / fmaxf(nrm, 1e-12f);
  int base = ((b * 32 + c) * 3) * NPTS + n;
  qx[base] = q0 * fac; qx[base + NPTS] = q1 * fac; qx[base + 2 * NPTS] = q2 * fac;
}

// ---------------- K2: kNN top-16 (by -||yi-yj||^2), self included ----------------
// block = 256, handles 4 rows n (same b). Distance phase shares the m-sweep loads;
// selection phase: wave w does iterative argmax for row w (wave-private, no barriers).
__global__ __launch_bounds__(256) void k2_knn(const float* __restrict__ y, int* __restrict__ idxout)
{
  __shared__ float as[4][96];
  __shared__ float nd[4][NPTS];
  int tid = threadIdx.x;
  int b = blockIdx.x / 192;
  int n0 = (blockIdx.x % 192) * 4;
  const float* yb = y + b * 96 * NPTS;
  for (int i = tid; i < 384; i += 256) {
    int j = i / 96, f = i % 96;
    as[j][f] = yb[f * NPTS + n0 + j];
  }
  __syncthreads();
  float sq0 = 0, sq1 = 0, sq2 = 0, sq3 = 0;
#pragma unroll 8
  for (int f = 0; f < 96; f++) {
    sq0 = fmaf(as[0][f], as[0][f], sq0);
    sq1 = fmaf(as[1][f], as[1][f], sq1);
    sq2 = fmaf(as[2][f], as[2][f], sq2);
    sq3 = fmaf(as[3][f], as[3][f], sq3);
  }
  for (int r = 0; r < 3; r++) {
    int m = r * 256 + tid;
    float in0 = 0, in1 = 0, in2 = 0, in3 = 0, sqm = 0;
#pragma unroll 8
    for (int f = 0; f < 96; f++) {
      float bm = yb[f * NPTS + m];
      in0 = fmaf(as[0][f], bm, in0);
      in1 = fmaf(as[1][f], bm, in1);
      in2 = fmaf(as[2][f], bm, in2);
      in3 = fmaf(as[3][f], bm, in3);
      sqm = fmaf(bm, bm, sqm);
    }
    nd[0][m] = 2.f * in0 - sq0 - sqm;
    nd[1][m] = 2.f * in1 - sq1 - sqm;
    nd[2][m] = 2.f * in2 - sq2 - sqm;
    nd[3][m] = 2.f * in3 - sq3 - sqm;
  }
  __syncthreads();
  int w = tid >> 6, lane = tid & 63;
  float* ndr = nd[w];
  int outbase = (b * NPTS + n0 + w) * 16;
  for (int it = 0; it < 16; it++) {
    float bv = -3e38f; int bi = 0;
#pragma unroll
    for (int r2 = 0; r2 < 12; r2++) {
      int m = r2 * 64 + lane;
      float v = ndr[m];
      if (v > bv || (v == bv && m < bi)) { bv = v; bi = m; }
    }
#pragma unroll
    for (int off = 1; off <= 32; off <<= 1) {
      float ov = __shfl_xor(bv, off);
      int oi = __shfl_xor(bi, off);
      if (ov > bv || (ov == bv && oi < bi)) { bv = ov; bi = oi; }
    }
    if (lane == 0) { idxout[outbase + it] = bi; ndr[bi] = -3e38f; }
  }
}

// ---------------- K3: Ksum (scaled) and Vsum ----------------
// block = 256 = 4 waves; wave handles one (b,n). lane = c (0..31) + 32*kh; kh-half does 8 neighbors.
// Weights packed float4 (Wkf,Wkd,Wvf,Wvd) in LDS as [cin][c] (conflict-free across lanes).
__global__ __launch_bounds__(256) void k3_kv(const float* __restrict__ y, const int* __restrict__ idxw,
    const float* __restrict__ Wkf, const float* __restrict__ Wkd,
    const float* __restrict__ Wvf, const float* __restrict__ Wvd,
    float* __restrict__ ksum, float* __restrict__ vsum)
{
  __shared__ float4 wpack[2048];        // [cin(64)][c(32)]
  __shared__ float cs[4][96];           // center features per wave
  __shared__ float4 gbuf[4][2][64];     // per wave, per kh: g[cin] -> (x,y,z,pad)
  int tid = threadIdx.x;
  for (int i = tid; i < 2048; i += 256) {
    int cin = i >> 5, c = i & 31;
    wpack[i] = make_float4(Wkf[c * 64 + cin], Wkd[c * 64 + cin],
                           Wvf[c * 64 + cin], Wvd[c * 64 + cin]);
  }
  int w = tid >> 6, lane = tid & 63;
  int kh = lane >> 5, c = lane & 31;
  int p = blockIdx.x * 4 + w;
  int b = p / NPTS, n = p % NPTS;
  const float* yb = y + b * 96 * NPTS;
  for (int t = lane; t < 96; t += 64) {
    float v = yb[t * NPTS + n];
    cs[w][t] = v;
    int ci = 32 + t / 3, d = t % 3;
    ((float*)&gbuf[w][0][ci])[d] = v;   // center half of g, constant over k
    ((float*)&gbuf[w][1][ci])[d] = v;
  }
  __syncthreads();
  float ks0 = 0, ks1 = 0, ks2 = 0, vs0 = 0, vs1 = 0, vs2 = 0;
  int ibase = (b * NPTS + n) * 16 + kh * 8;
  for (int j8 = 0; j8 < 8; j8++) {
    int m = idxw[ibase + j8];
    for (int t = c; t < 96; t += 32) {
      ((float*)&gbuf[w][kh][t / 3])[t % 3] = yb[t * NPTS + m] - cs[w][t];
    }
    __syncthreads();
    float kf0 = 0, kf1 = 0, kf2 = 0, kd0 = 0, kd1 = 0, kd2 = 0;
    float vf0 = 0, vf1 = 0, vf2 = 0, vd0 = 0, vd1 = 0, vd2 = 0;
#pragma unroll 4
    for (int cin = 0; cin < 64; cin++) {
      float4 wv = wpack[(cin << 5) + c];
      float4 gg = gbuf[w][kh][cin];
      kf0 = fmaf(wv.x, gg.x, kf0); kf1 = fmaf(wv.x, gg.y, kf1); kf2 = fmaf(wv.x, gg.z, kf2);
      kd0 = fmaf(wv.y, gg.x, kd0); kd1 = fmaf(wv.y, gg.y, kd1); kd2 = fmaf(wv.y, gg.z, kd2);
      vf0 = fmaf(wv.z, gg.x, vf0); vf1 = fmaf(wv.z, gg.y, vf1); vf2 = fmaf(wv.z, gg.z, vf2);
      vd0 = fmaf(wv.w, gg.x, vd0); vd1 = fmaf(wv.w, gg.y, vd1); vd2 = fmaf(wv.w, gg.z, vd2);
    }
    // K branch: leaky + channel_equi_vec_normalize, accumulate
    float dot = kf0 * kd0 + kf1 * kd1 + kf2 * kd2;
    float dsq = kd0 * kd0 + kd1 * kd1 + kd2 * kd2;
    float k0 = kf0, k1 = kf1, k2 = kf2;
    if (dot < 0.f) { float r = 0.8f * dot / (dsq + 1e-6f); k0 -= r * kd0; k1 -= r * kd1; k2 -= r * kd2; }
    float nrm = sqrtf(k0 * k0 + k1 * k1 + k2 * k2);
    float n2 = nrm * nrm;
#pragma unroll
    for (int mm = 1; mm <= 16; mm <<= 1) n2 += __shfl_xor(n2, mm);
    float fac = (nrm / fmaxf(sqrtf(n2), 1e-12f)) / fmaxf(nrm, 1e-12f);
    ks0 = fmaf(k0, fac, ks0); ks1 = fmaf(k1, fac, ks1); ks2 = fmaf(k2, fac, ks2);
    // V branch: leaky only, accumulate
    float dotv = vf0 * vd0 + vf1 * vd1 + vf2 * vd2;
    float dsqv = vd0 * vd0 + vd1 * vd1 + vd2 * vd2;
    float v0 = vf0, v1 = vf1, v2 = vf2;
    if (dotv < 0.f) { float r = 0.8f * dotv / (dsqv + 1e-6f); v0 -= r * vd0; v1 -= r * vd1; v2 -= r * vd2; }
    vs0 += v0; vs1 += v1; vs2 += v2;
    __syncthreads();
  }
  ks0 += __shfl_xor(ks0, 32); ks1 += __shfl_xor(ks1, 32); ks2 += __shfl_xor(ks2, 32);
  vs0 += __shfl_xor(vs0, 32); vs1 += __shfl_xor(vs1, 32); vs2 += __shfl_xor(vs2, 32);
  if (kh == 0) {
    int base = ((b * 32 + c) * 3) * NPTS + n;
    ksum[base] = ks0 * SCALE; ksum[base + NPTS] = ks1 * SCALE; ksum[base + 2 * NPTS] = ks2 * SCALE;
    vsum[base] = vs0; vsum[base + NPTS] = vs1; vsum[base + 2 * NPTS] = vs2;
  }
}

// ---------------- K4: attention softmax + output ----------------
// grid = 192 slices * 3 chunks; block 256; thread = one n. s,V staged in LDS (broadcast reads).
__global__ __launch_bounds__(256) void k4_attn(const float* __restrict__ x,
    const float* __restrict__ qx, const float* __restrict__ ks, const float* __restrict__ vs,
    float* __restrict__ out)
{
  __shared__ float4 s4[192], v4[192];
  __shared__ float rmax[4], rmin[4];
  __shared__ float bmax_s, bmin_s;
  int tid = threadIdx.x;
  int sl = blockIdx.x / 3, chunk = blockIdx.x % 3;
  const float* srow = ks + sl * NPTS;
  const float* vrow = vs + sl * NPTS;
  float lmax = -3e38f, lmin = 3e38f;
  for (int i = tid; i < NPTS; i += 256) {
    float sv = srow[i], vv = vrow[i];
    ((float*)s4)[i] = sv; ((float*)v4)[i] = vv;
    lmax = fmaxf(lmax, sv); lmin = fminf(lmin, sv);
  }
#pragma unroll
  for (int off = 1; off <= 32; off <<= 1) {
    lmax = fmaxf(lmax, __shfl_xor(lmax, off));
    lmin = fminf(lmin, __shfl_xor(lmin, off));
  }
  int lane = tid & 63, wid = tid >> 6;
  if (lane == 0) { rmax[wid] = lmax; rmin[wid] = lmin; }
  __syncthreads();
  if (tid == 0) {
    float a = rmax[0], bm = rmin[0];
    for (int i = 1; i < 4; i++) { a = fmaxf(a, rmax[i]); bm = fminf(bm, rmin[i]); }
    bmax_s = a; bmin_s = bm;
  }
  __syncthreads();
  int n = chunk * 256 + tid;
  float q = qx[sl * NPTS + n];
  float ms = fmaxf(q * bmax_s, q * bmin_s);   // max over m of q*s[m]
  float num = 0.f, den = 0.f;
  for (int m4 = 0; m4 < 192; m4++) {
    float4 ss = s4[m4], vv = v4[m4];
    float e0 = __expf(fmaf(q, ss.x, -ms));
    float e1 = __expf(fmaf(q, ss.y, -ms));
    float e2 = __expf(fmaf(q, ss.z, -ms));
    float e3 = __expf(fmaf(q, ss.w, -ms));
    num = fmaf(e0, vv.x, num); den += e0;
    num = fmaf(e1, vv.y, num); den += e1;
    num = fmaf(e2, vv.z, num); den += e2;
    num = fmaf(e3, vv.w, num); den += e3;
  }
  out[sl * NPTS + n] = x[sl * NPTS + n] + num / den;
}

extern "C" void kernel_launch(void* const* d_in, const int* in_sizes, int n_in,
                              void* d_out, int out_size, void* d_ws, size_t ws_size,
                              hipStream_t stream) {
  const float* x   = (const float*)d_in[0];
  const float* y   = (const float*)d_in[1];
  const float* Wqf = (const float*)d_in[2];
  const float* Wqd = (const float*)d_in[3];
  const float* Wkf = (const float*)d_in[4];
  const float* Wkd = (const float*)d_in[5];
  const float* Wvf = (const float*)d_in[6];
  const float* Wvd = (const float*)d_in[7];
  float* out = (float*)d_out;

  float* qx   = (float*)d_ws;            // 147456 floats
  float* ksum = qx + 147456;             // 147456 floats (pre-scaled)
  float* vsum = ksum + 147456;           // 147456 floats
  int*   idx  = (int*)(vsum + 147456);   // 24576 ints

  k1_qx  <<<192, 256, 0, stream>>>(x, Wqf, Wqd, qx);
  k2_knn <<<384, 256, 0, stream>>>(y, idx);
  k3_kv  <<<384, 256, 0, stream>>>(y, idx, Wkf, Wkd, Wvf, Wvd, ksum, vsum);
  k4_attn<<<576, 256, 0, stream>>>(x, qx, ksum, vsum, out);
}

// Round 2
// 145.854 us; speedup vs baseline: 1.1415x; 1.1415x over previous
//
#include <hip/hip_runtime.h>
#include <hip/hip_bf16.h>

#define NPTS 768
#define SCALE 0.10206207261596575f  // 1/sqrt(96)

// ---------------- K1: Qx = channel_equi_vec_normalize(vn_linear_leaky(x, Wq_f, Wq_d)) ----------------
// block = 256 = 8 groups of 32 lanes; group handles one (b,n); lane = out-channel c.
__global__ __launch_bounds__(256) void k1_qx(const float* __restrict__ x,
    const float* __restrict__ Wf, const float* __restrict__ Wd, float* __restrict__ qx)
{
  __shared__ float2 w2[1024];     // [cin][c] packed (Wf, Wd)
  __shared__ float4 xs[8][32];    // per group: [cin] -> (x,y,z,pad)
  int tid = threadIdx.x;
  for (int i = tid; i < 1024; i += 256) {
    int cin = i >> 5, c = i & 31;
    w2[i] = make_float2(Wf[c * 32 + cin], Wd[c * 32 + cin]);
  }
  int g = tid >> 5, s = tid & 31;
  int p = blockIdx.x * 8 + g;
  int b = p / NPTS, n = p % NPTS;
  for (int t = s; t < 96; t += 32) {
    float v = x[(b * 96 + t) * NPTS + n];
    ((float*)&xs[g][t / 3])[t % 3] = v;
  }
  __syncthreads();
  int c = s;
  float pf0 = 0, pf1 = 0, pf2 = 0, pd0 = 0, pd1 = 0, pd2 = 0;
#pragma unroll
  for (int cin = 0; cin < 32; cin++) {
    float2 w = w2[(cin << 5) + c];
    float4 xv = xs[g][cin];
    pf0 = fmaf(w.x, xv.x, pf0); pf1 = fmaf(w.x, xv.y, pf1); pf2 = fmaf(w.x, xv.z, pf2);
    pd0 = fmaf(w.y, xv.x, pd0); pd1 = fmaf(w.y, xv.y, pd1); pd2 = fmaf(w.y, xv.z, pd2);
  }
  float dot = pf0 * pd0 + pf1 * pd1 + pf2 * pd2;
  float dsq = pd0 * pd0 + pd1 * pd1 + pd2 * pd2;
  float q0 = pf0, q1 = pf1, q2 = pf2;
  if (dot < 0.f) {
    float r = 0.8f * dot / (dsq + 1e-6f);
    q0 -= r * pd0; q1 -= r * pd1; q2 -= r * pd2;
  }
  float nrm = sqrtf(q0 * q0 + q1 * q1 + q2 * q2);
  float n2 = nrm * nrm;
#pragma unroll
  for (int m = 1; m <= 16; m <<= 1) n2 += __shfl_xor(n2, m);
  float ch = sqrtf(n2);
  float fac = (nrm / fmaxf(ch, 1e-12f)) / fmaxf(nrm, 1e-12f);
  int base = ((b * 32 + c) * 3) * NPTS + n;
  qx[base] = q0 * fac; qx[base + NPTS] = q1 * fac; qx[base + 2 * NPTS] = q2 * fac;
}

// ---------------- K2: kNN top-16 (by -||yi-yj||^2), self included ----------------
__global__ __launch_bounds__(256) void k2_knn(const float* __restrict__ y, int* __restrict__ idxout)
{
  __shared__ float as[4][96];
  __shared__ float nd[4][NPTS];
  int tid = threadIdx.x;
  int b = blockIdx.x / 192;
  int n0 = (blockIdx.x % 192) * 4;
  const float* yb = y + b * 96 * NPTS;
  for (int i = tid; i < 384; i += 256) {
    int j = i / 96, f = i % 96;
    as[j][f] = yb[f * NPTS + n0 + j];
  }
  __syncthreads();
  float sq0 = 0, sq1 = 0, sq2 = 0, sq3 = 0;
#pragma unroll 8
  for (int f = 0; f < 96; f++) {
    sq0 = fmaf(as[0][f], as[0][f], sq0);
    sq1 = fmaf(as[1][f], as[1][f], sq1);
    sq2 = fmaf(as[2][f], as[2][f], sq2);
    sq3 = fmaf(as[3][f], as[3][f], sq3);
  }
  for (int r = 0; r < 3; r++) {
    int m = r * 256 + tid;
    float in0 = 0, in1 = 0, in2 = 0, in3 = 0, sqm = 0;
#pragma unroll 8
    for (int f = 0; f < 96; f++) {
      float bm = yb[f * NPTS + m];
      in0 = fmaf(as[0][f], bm, in0);
      in1 = fmaf(as[1][f], bm, in1);
      in2 = fmaf(as[2][f], bm, in2);
      in3 = fmaf(as[3][f], bm, in3);
      sqm = fmaf(bm, bm, sqm);
    }
    nd[0][m] = 2.f * in0 - sq0 - sqm;
    nd[1][m] = 2.f * in1 - sq1 - sqm;
    nd[2][m] = 2.f * in2 - sq2 - sqm;
    nd[3][m] = 2.f * in3 - sq3 - sqm;
  }
  __syncthreads();
  int w = tid >> 6, lane = tid & 63;
  float* ndr = nd[w];
  int outbase = (b * NPTS + n0 + w) * 16;
  for (int it = 0; it < 16; it++) {
    float bv = -3e38f; int bi = 0;
#pragma unroll
    for (int r2 = 0; r2 < 12; r2++) {
      int m = r2 * 64 + lane;
      float v = ndr[m];
      if (v > bv || (v == bv && m < bi)) { bv = v; bi = m; }
    }
#pragma unroll
    for (int off = 1; off <= 32; off <<= 1) {
      float ov = __shfl_xor(bv, off);
      int oi = __shfl_xor(bi, off);
      if (ov > bv || (ov == bv && oi < bi)) { bv = ov; bi = oi; }
    }
    if (lane == 0) { idxout[outbase + it] = bi; ndr[bi] = -3e38f; }
  }
}

// ---------------- K3a: per-point transforms ----------------
// P[m] = W_L * y[m], R[n] = (W_R - W_L) * y[n] for the 4 mats (Kf, Kd, Vf, Vd).
// Layout per point per channel c: 12 floats [kf0,kf1,kf2,kd0,kd1,kd2,vf0,vf1,vf2,vd0,vd1,vd2].
__global__ __launch_bounds__(256) void k3a_pre(const float* __restrict__ y,
    const float* __restrict__ Wkf, const float* __restrict__ Wkd,
    const float* __restrict__ Wvf, const float* __restrict__ Wvd,
    float* __restrict__ Pb, float* __restrict__ Rb)
{
  __shared__ float4 wLs[1024];   // [cin][c] = (kfL, kdL, vfL, vdL)
  __shared__ float4 wDs[1024];   // [cin][c] = (kfR-kfL, ...)
  __shared__ float4 xs[8][32];
  int tid = threadIdx.x;
  for (int i = tid; i < 1024; i += 256) {
    int cin = i >> 5, c = i & 31;
    float kfL = Wkf[c * 64 + cin], kdL = Wkd[c * 64 + cin];
    float vfL = Wvf[c * 64 + cin], vdL = Wvd[c * 64 + cin];
    wLs[i] = make_float4(kfL, kdL, vfL, vdL);
    wDs[i] = make_float4(Wkf[c * 64 + 32 + cin] - kfL, Wkd[c * 64 + 32 + cin] - kdL,
                         Wvf[c * 64 + 32 + cin] - vfL, Wvd[c * 64 + 32 + cin] - vdL);
  }
  int g = tid >> 5, c = tid & 31;
  int p = blockIdx.x * 8 + g;
  int b = p / NPTS, n = p % NPTS;
  for (int t = c; t < 96; t += 32) {
    float v = y[(b * 96 + t) * NPTS + n];
    ((float*)&xs[g][t / 3])[t % 3] = v;
  }
  __syncthreads();
  float lkf0 = 0, lkf1 = 0, lkf2 = 0, lkd0 = 0, lkd1 = 0, lkd2 = 0;
  float lvf0 = 0, lvf1 = 0, lvf2 = 0, lvd0 = 0, lvd1 = 0, lvd2 = 0;
  float dkf0 = 0, dkf1 = 0, dkf2 = 0, dkd0 = 0, dkd1 = 0, dkd2 = 0;
  float dvf0 = 0, dvf1 = 0, dvf2 = 0, dvd0 = 0, dvd1 = 0, dvd2 = 0;
#pragma unroll 8
  for (int cin = 0; cin < 32; cin++) {
    float4 wl = wLs[(cin << 5) + c];
    float4 wd = wDs[(cin << 5) + c];
    float4 xv = xs[g][cin];
    lkf0 = fmaf(wl.x, xv.x, lkf0); lkf1 = fmaf(wl.x, xv.y, lkf1); lkf2 = fmaf(wl.x, xv.z, lkf2);
    lkd0 = fmaf(wl.y, xv.x, lkd0); lkd1 = fmaf(wl.y, xv.y, lkd1); lkd2 = fmaf(wl.y, xv.z, lkd2);
    lvf0 = fmaf(wl.z, xv.x, lvf0); lvf1 = fmaf(wl.z, xv.y, lvf1); lvf2 = fmaf(wl.z, xv.z, lvf2);
    lvd0 = fmaf(wl.w, xv.x, lvd0); lvd1 = fmaf(wl.w, xv.y, lvd1); lvd2 = fmaf(wl.w, xv.z, lvd2);
    dkf0 = fmaf(wd.x, xv.x, dkf0); dkf1 = fmaf(wd.x, xv.y, dkf1); dkf2 = fmaf(wd.x, xv.z, dkf2);
    dkd0 = fmaf(wd.y, xv.x, dkd0); dkd1 = fmaf(wd.y, xv.y, dkd1); dkd2 = fmaf(wd.y, xv.z, dkd2);
    dvf0 = fmaf(wd.z, xv.x, dvf0); dvf1 = fmaf(wd.z, xv.y, dvf1); dvf2 = fmaf(wd.z, xv.z, dvf2);
    dvd0 = fmaf(wd.w, xv.x, dvd0); dvd1 = fmaf(wd.w, xv.y, dvd1); dvd2 = fmaf(wd.w, xv.z, dvd2);
  }
  size_t base = ((size_t)(b * NPTS + n) * 32 + c) * 12;
  float4* Pp = (float4*)(Pb + base);
  Pp[0] = make_float4(lkf0, lkf1, lkf2, lkd0);
  Pp[1] = make_float4(lkd1, lkd2, lvf0, lvf1);
  Pp[2] = make_float4(lvf2, lvd0, lvd1, lvd2);
  float4* Rp = (float4*)(Rb + base);
  Rp[0] = make_float4(dkf0, dkf1, dkf2, dkd0);
  Rp[1] = make_float4(dkd1, dkd2, dvf0, dvf1);
  Rp[2] = make_float4(dvf2, dvd0, dvd1, dvd2);
}

// ---------------- K3b: gather + nonlinearity + accumulate ----------------
// block = 256 = 4 waves; wave = one (b,n); lane = c(0..31) + 32*kh; each half does 8 neighbors.
// No LDS, no barriers: per neighbor, load P[m] (48B/lane contiguous per half) + register R[n].
__global__ __launch_bounds__(256) void k3b_kv(const float* __restrict__ Pb,
    const float* __restrict__ Rb, const int* __restrict__ idxw,
    float* __restrict__ ksum, float* __restrict__ vsum)
{
  int tid = threadIdx.x;
  int w = tid >> 6, lane = tid & 63, kh = lane >> 5, c = lane & 31;
  int p = blockIdx.x * 4 + w;
  int b = p / NPTS, n = p % NPTS;
  const float4* Rp = (const float4*)(Rb + ((size_t)(b * NPTS + n) * 32 + c) * 12);
  float4 r0 = Rp[0], r1 = Rp[1], r2 = Rp[2];
  int ibase = (b * NPTS + n) * 16 + kh * 8;
  int4 ia = *(const int4*)(idxw + ibase);
  int4 ib = *(const int4*)(idxw + ibase + 4);
  int ms[8] = {ia.x, ia.y, ia.z, ia.w, ib.x, ib.y, ib.z, ib.w};
  float ks0 = 0, ks1 = 0, ks2 = 0, vs0 = 0, vs1 = 0, vs2 = 0;
#pragma unroll 4
  for (int j = 0; j < 8; j++) {
    const float4* Pp = (const float4*)(Pb + ((size_t)(b * NPTS + ms[j]) * 32 + c) * 12);
    float4 p0 = Pp[0], p1 = Pp[1], p2 = Pp[2];
    float kf0 = p0.x + r0.x, kf1 = p0.y + r0.y, kf2 = p0.z + r0.z;
    float kd0 = p0.w + r0.w, kd1 = p1.x + r1.x, kd2 = p1.y + r1.y;
    float vf0 = p1.z + r1.z, vf1 = p1.w + r1.w, vf2 = p2.x + r2.x;
    float vd0 = p2.y + r2.y, vd1 = p2.z + r2.z, vd2 = p2.w + r2.w;
    // K branch: leaky + channel_equi_vec_normalize, accumulate
    float dot = kf0 * kd0 + kf1 * kd1 + kf2 * kd2;
    float dsq = kd0 * kd0 + kd1 * kd1 + kd2 * kd2;
    float k0 = kf0, k1 = kf1, k2 = kf2;
    if (dot < 0.f) { float r = 0.8f * dot / (dsq + 1e-6f); k0 -= r * kd0; k1 -= r * kd1; k2 -= r * kd2; }
    float nrm = sqrtf(k0 * k0 + k1 * k1 + k2 * k2);
    float n2 = nrm * nrm;
#pragma unroll
    for (int mm = 1; mm <= 16; mm <<= 1) n2 += __shfl_xor(n2, mm);
    float fac = (nrm / fmaxf(sqrtf(n2), 1e-12f)) / fmaxf(nrm, 1e-12f);
    ks0 = fmaf(k0, fac, ks0); ks1 = fmaf(k1, fac, ks1); ks2 = fmaf(k2, fac, ks2);
    // V branch: leaky only, accumulate
    float dotv = vf0 * vd0 + vf1 * vd1 + vf2 * vd2;
    float dsqv = vd0 * vd0 + vd1 * vd1 + vd2 * vd2;
    float v0 = vf0, v1 = vf1, v2 = vf2;
    if (dotv < 0.f) { float r = 0.8f * dotv / (dsqv + 1e-6f); v0 -= r * vd0; v1 -= r * vd1; v2 -= r * vd2; }
    vs0 += v0; vs1 += v1; vs2 += v2;
  }
  ks0 += __shfl_xor(ks0, 32); ks1 += __shfl_xor(ks1, 32); ks2 += __shfl_xor(ks2, 32);
  vs0 += __shfl_xor(vs0, 32); vs1 += __shfl_xor(vs1, 32); vs2 += __shfl_xor(vs2, 32);
  if (kh == 0) {
    int base = ((b * 32 + c) * 3) * NPTS + n;
    ksum[base] = ks0 * SCALE; ksum[base + NPTS] = ks1 * SCALE; ksum[base + 2 * NPTS] = ks2 * SCALE;
    vsum[base] = vs0; vsum[base + NPTS] = vs1; vsum[base + 2 * NPTS] = vs2;
  }
}

// ---------------- K4: attention softmax + output ----------------
__global__ __launch_bounds__(256) void k4_attn(const float* __restrict__ x,
    const float* __restrict__ qx, const float* __restrict__ ks, const float* __restrict__ vs,
    float* __restrict__ out)
{
  __shared__ float4 s4[192], v4[192];
  __shared__ float rmax[4], rmin[4];
  __shared__ float bmax_s, bmin_s;
  int tid = threadIdx.x;
  int sl = blockIdx.x / 3, chunk = blockIdx.x % 3;
  const float* srow = ks + sl * NPTS;
  const float* vrow = vs + sl * NPTS;
  float lmax = -3e38f, lmin = 3e38f;
  for (int i = tid; i < NPTS; i += 256) {
    float sv = srow[i], vv = vrow[i];
    ((float*)s4)[i] = sv; ((float*)v4)[i] = vv;
    lmax = fmaxf(lmax, sv); lmin = fminf(lmin, sv);
  }
#pragma unroll
  for (int off = 1; off <= 32; off <<= 1) {
    lmax = fmaxf(lmax, __shfl_xor(lmax, off));
    lmin = fminf(lmin, __shfl_xor(lmin, off));
  }
  int lane = tid & 63, wid = tid >> 6;
  if (lane == 0) { rmax[wid] = lmax; rmin[wid] = lmin; }
  __syncthreads();
  if (tid == 0) {
    float a = rmax[0], bm = rmin[0];
    for (int i = 1; i < 4; i++) { a = fmaxf(a, rmax[i]); bm = fminf(bm, rmin[i]); }
    bmax_s = a; bmin_s = bm;
  }
  __syncthreads();
  int n = chunk * 256 + tid;
  float q = qx[sl * NPTS + n];
  float ms = fmaxf(q * bmax_s, q * bmin_s);   // max over m of q*s[m]
  float num = 0.f, den = 0.f;
  for (int m4 = 0; m4 < 192; m4++) {
    float4 ss = s4[m4], vv = v4[m4];
    float e0 = __expf(fmaf(q, ss.x, -ms));
    float e1 = __expf(fmaf(q, ss.y, -ms));
    float e2 = __expf(fmaf(q, ss.z, -ms));
    float e3 = __expf(fmaf(q, ss.w, -ms));
    num = fmaf(e0, vv.x, num); den += e0;
    num = fmaf(e1, vv.y, num); den += e1;
    num = fmaf(e2, vv.z, num); den += e2;
    num = fmaf(e3, vv.w, num); den += e3;
  }
  out[sl * NPTS + n] = x[sl * NPTS + n] + num / den;
}

extern "C" void kernel_launch(void* const* d_in, const int* in_sizes, int n_in,
                              void* d_out, int out_size, void* d_ws, size_t ws_size,
                              hipStream_t stream) {
  const float* x   = (const float*)d_in[0];
  const float* y   = (const float*)d_in[1];
  const float* Wqf = (const float*)d_in[2];
  const float* Wqd = (const float*)d_in[3];
  const float* Wkf = (const float*)d_in[4];
  const float* Wkd = (const float*)d_in[5];
  const float* Wvf = (const float*)d_in[6];
  const float* Wvd = (const float*)d_in[7];
  float* out = (float*)d_out;

  float* qx   = (float*)d_ws;            // 147456
  float* ksum = qx + 147456;             // 147456 (pre-scaled)
  float* vsum = ksum + 147456;           // 147456
  int*   idx  = (int*)(vsum + 147456);   // 24576 ints
  float* Pb   = (float*)(idx + 24576);   // 589824
  float* Rb   = Pb + 589824;             // 589824

  k1_qx  <<<192, 256, 0, stream>>>(x, Wqf, Wqd, qx);
  k2_knn <<<384, 256, 0, stream>>>(y, idx);
  k3a_pre<<<192, 256, 0, stream>>>(y, Wkf, Wkd, Wvf, Wvd, Pb, Rb);
  k3b_kv <<<384, 256, 0, stream>>>(Pb, Rb, idx, ksum, vsum);
  k4_attn<<<576, 256, 0, stream>>>(x, qx, ksum, vsum, out);
}

// Round 4
// 140.778 us; speedup vs baseline: 1.1826x; 1.0361x over previous
//
#include <hip/hip_runtime.h>
#include <hip/hip_bf16.h>

#define NPTS 768
// 1/sqrt(96) * log2(e): pre-scales ksum so k4 can use raw v_exp_f32 (exp2)
#define SCALE2 0.14724444f

// ---------------- K13: fused per-point transforms ----------------
// bid < 192 : Qx path (x -> qx), 8 points/block, 32 lanes/point
// bid >= 192: P/R path (y -> Pb, Rb), 4 points/block, 64 lanes/point
//             half-wave 0 computes P = W_L*y, half-wave 1 computes R = (W_R-W_L)*y
__global__ __launch_bounds__(256) void k13_pre(const float* __restrict__ x,
    const float* __restrict__ y,
    const float* __restrict__ Wqf, const float* __restrict__ Wqd,
    const float* __restrict__ Wkf, const float* __restrict__ Wkd,
    const float* __restrict__ Wvf, const float* __restrict__ Wvd,
    float* __restrict__ qx, float* __restrict__ Pb, float* __restrict__ Rb)
{
  __shared__ __align__(16) char smem[34816];
  int tid = threadIdx.x;
  if (blockIdx.x < 192) {
    // ---------- Qx path ----------
    float2* w2 = (float2*)smem;                       // [cin][c] (Wqf, Wqd), 8KB
    float4 (*xs)[32] = (float4(*)[32])(smem + 8192);  // [group][cin], 4KB
    for (int i = tid; i < 1024; i += 256) {
      int cin = i >> 5, c = i & 31;
      w2[i] = make_float2(Wqf[c * 32 + cin], Wqd[c * 32 + cin]);
    }
    int g = tid >> 5, c = tid & 31;
    int p = blockIdx.x * 8 + g;
    int b = p / NPTS, n = p % NPTS;
    for (int t = c; t < 96; t += 32) {
      float v = x[(b * 96 + t) * NPTS + n];
      ((float*)&xs[g][t / 3])[t % 3] = v;
    }
    __syncthreads();
    float pf0 = 0, pf1 = 0, pf2 = 0, pd0 = 0, pd1 = 0, pd2 = 0;
#pragma unroll
    for (int cin = 0; cin < 32; cin++) {
      float2 w = w2[(cin << 5) + c];
      float4 xv = xs[g][cin];
      pf0 = fmaf(w.x, xv.x, pf0); pf1 = fmaf(w.x, xv.y, pf1); pf2 = fmaf(w.x, xv.z, pf2);
      pd0 = fmaf(w.y, xv.x, pd0); pd1 = fmaf(w.y, xv.y, pd1); pd2 = fmaf(w.y, xv.z, pd2);
    }
    float dot = pf0 * pd0 + pf1 * pd1 + pf2 * pd2;
    float dsq = pd0 * pd0 + pd1 * pd1 + pd2 * pd2;
    float q0 = pf0, q1 = pf1, q2 = pf2;
    if (dot < 0.f) {
      float r = 0.8f * dot / (dsq + 1e-6f);
      q0 -= r * pd0; q1 -= r * pd1; q2 -= r * pd2;
    }
    float nrm = sqrtf(q0 * q0 + q1 * q1 + q2 * q2);
    float n2 = nrm * nrm;
#pragma unroll
    for (int m = 1; m <= 16; m <<= 1) n2 += __shfl_xor(n2, m);
    float fac = (nrm / fmaxf(sqrtf(n2), 1e-12f)) / fmaxf(nrm, 1e-12f);
    int base = ((b * 32 + c) * 3) * NPTS + n;
    qx[base] = q0 * fac; qx[base + NPTS] = q1 * fac; qx[base + 2 * NPTS] = q2 * fac;
  } else {
    // ---------- P/R path ----------
    float4* wLs = (float4*)smem;                        // [cin][c] = (kfL,kdL,vfL,vdL), 16KB (1024 entries)
    float4* wDs = (float4*)(smem + 16384);              // [cin][c] = R-L deltas, 16KB (1024 entries)
    float4 (*xs)[32] = (float4(*)[32])(smem + 32768);   // [pt][cin], 2KB
    for (int i = tid; i < 1024; i += 256) {             // i < 1024: wLs/wDs are each 1024 entries!
      int cin = i >> 5, c = i & 31;
      float kfL = Wkf[c * 64 + cin], kdL = Wkd[c * 64 + cin];
      float vfL = Wvf[c * 64 + cin], vdL = Wvd[c * 64 + cin];
      wLs[i] = make_float4(kfL, kdL, vfL, vdL);
      wDs[i] = make_float4(Wkf[c * 64 + 32 + cin] - kfL, Wkd[c * 64 + 32 + cin] - kdL,
                           Wvf[c * 64 + 32 + cin] - vfL, Wvd[c * 64 + 32 + cin] - vdL);
    }
    int g = tid >> 6, lane = tid & 63, half = lane >> 5, c = lane & 31;
    int p = (blockIdx.x - 192) * 4 + g;
    int b = p / NPTS, n = p % NPTS;
    for (int t = lane; t < 96; t += 64) {
      float v = y[(b * 96 + t) * NPTS + n];
      ((float*)&xs[g][t / 3])[t % 3] = v;
    }
    __syncthreads();
    const float4* wsel = half ? wDs : wLs;
    float kf0 = 0, kf1 = 0, kf2 = 0, kd0 = 0, kd1 = 0, kd2 = 0;
    float vf0 = 0, vf1 = 0, vf2 = 0, vd0 = 0, vd1 = 0, vd2 = 0;
#pragma unroll 8
    for (int cin = 0; cin < 32; cin++) {
      float4 wv = wsel[(cin << 5) + c];
      float4 xv = xs[g][cin];
      kf0 = fmaf(wv.x, xv.x, kf0); kf1 = fmaf(wv.x, xv.y, kf1); kf2 = fmaf(wv.x, xv.z, kf2);
      kd0 = fmaf(wv.y, xv.x, kd0); kd1 = fmaf(wv.y, xv.y, kd1); kd2 = fmaf(wv.y, xv.z, kd2);
      vf0 = fmaf(wv.z, xv.x, vf0); vf1 = fmaf(wv.z, xv.y, vf1); vf2 = fmaf(wv.z, xv.z, vf2);
      vd0 = fmaf(wv.w, xv.x, vd0); vd1 = fmaf(wv.w, xv.y, vd1); vd2 = fmaf(wv.w, xv.z, vd2);
    }
    float* dst = half ? Rb : Pb;
    size_t base = ((size_t)(b * NPTS + n) * 32 + c) * 12;
    float4* Dp = (float4*)(dst + base);
    Dp[0] = make_float4(kf0, kf1, kf2, kd0);
    Dp[1] = make_float4(kd1, kd2, vf0, vf1);
    Dp[2] = make_float4(vf2, vd0, vd1, vd2);
  }
}

// ---------------- K2: kNN top-16 via exact 64-bit keys ----------------
// Distance phase: 4 rows/block, thread = column; monotone float->u32 map stored in LDS.
// Selection: wave w selects row w; 12 keys/lane in registers as
// key64 = (monotone_u32 << 10) | (1023 - m)  -- exact distance order + smaller-m tie-break.
__global__ __launch_bounds__(256) void k2_knn(const float* __restrict__ y, int* __restrict__ idxout)
{
  __shared__ float as[4][96];
  __shared__ unsigned int kd[4][NPTS];
  int tid = threadIdx.x;
  int b = blockIdx.x / 192;
  int n0 = (blockIdx.x % 192) * 4;
  const float* yb = y + b * 96 * NPTS;
  for (int i = tid; i < 384; i += 256) {
    int j = i / 96, f = i % 96;
    as[j][f] = yb[f * NPTS + n0 + j];
  }
  __syncthreads();
  float sq0 = 0, sq1 = 0, sq2 = 0, sq3 = 0;
#pragma unroll 8
  for (int f = 0; f < 96; f++) {
    sq0 = fmaf(as[0][f], as[0][f], sq0);
    sq1 = fmaf(as[1][f], as[1][f], sq1);
    sq2 = fmaf(as[2][f], as[2][f], sq2);
    sq3 = fmaf(as[3][f], as[3][f], sq3);
  }
  for (int r = 0; r < 3; r++) {
    int m = r * 256 + tid;
    float in0 = 0, in1 = 0, in2 = 0, in3 = 0, sqm = 0;
#pragma unroll 8
    for (int f = 0; f < 96; f++) {
      float bm = yb[f * NPTS + m];
      in0 = fmaf(as[0][f], bm, in0);
      in1 = fmaf(as[1][f], bm, in1);
      in2 = fmaf(as[2][f], bm, in2);
      in3 = fmaf(as[3][f], bm, in3);
      sqm = fmaf(bm, bm, sqm);
    }
    float d0 = 2.f * in0 - sq0 - sqm;
    float d1 = 2.f * in1 - sq1 - sqm;
    float d2 = 2.f * in2 - sq2 - sqm;
    float d3 = 2.f * in3 - sq3 - sqm;
#pragma unroll
    for (int j = 0; j < 4; j++) {
      float v = (j == 0) ? d0 : (j == 1) ? d1 : (j == 2) ? d2 : d3;
      unsigned int u = __float_as_uint(v);
      u = (u & 0x80000000u) ? ~u : (u | 0x80000000u);   // monotone map (exact)
      kd[j][m] = u;
    }
  }
  __syncthreads();
  int w = tid >> 6, lane = tid & 63;
  unsigned long long kk[12];
#pragma unroll
  for (int j = 0; j < 12; j++) {
    int m = lane + 64 * j;
    kk[j] = ((unsigned long long)kd[w][m] << 10) | (unsigned)(1023 - m);
  }
  int outbase = (b * NPTS + n0 + w) * 16;
  for (int it = 0; it < 16; it++) {
    unsigned long long a0 = kk[0] > kk[1] ? kk[0] : kk[1];
    unsigned long long a1 = kk[2] > kk[3] ? kk[2] : kk[3];
    unsigned long long a2 = kk[4] > kk[5] ? kk[4] : kk[5];
    unsigned long long a3 = kk[6] > kk[7] ? kk[6] : kk[7];
    unsigned long long a4 = kk[8] > kk[9] ? kk[8] : kk[9];
    unsigned long long a5 = kk[10] > kk[11] ? kk[10] : kk[11];
    unsigned long long b0 = a0 > a1 ? a0 : a1;
    unsigned long long b1 = a2 > a3 ? a2 : a3;
    unsigned long long b2 = a4 > a5 ? a4 : a5;
    unsigned long long best = b0 > b1 ? b0 : b1;
    best = best > b2 ? best : b2;
#pragma unroll
    for (int off = 1; off <= 32; off <<= 1) {
      unsigned long long o = __shfl_xor(best, off);
      best = o > best ? o : best;
    }
    int wm = 1023 - (int)(best & 1023u);
    if (lane == 0) idxout[outbase + it] = wm;
    int jj = wm >> 6;                 // wave-uniform
    bool me = (lane == (wm & 63));
    switch (jj) {
      case 0:  kk[0]  = me ? 0ull : kk[0];  break;
      case 1:  kk[1]  = me ? 0ull : kk[1];  break;
      case 2:  kk[2]  = me ? 0ull : kk[2];  break;
      case 3:  kk[3]  = me ? 0ull : kk[3];  break;
      case 4:  kk[4]  = me ? 0ull : kk[4];  break;
      case 5:  kk[5]  = me ? 0ull : kk[5];  break;
      case 6:  kk[6]  = me ? 0ull : kk[6];  break;
      case 7:  kk[7]  = me ? 0ull : kk[7];  break;
      case 8:  kk[8]  = me ? 0ull : kk[8];  break;
      case 9:  kk[9]  = me ? 0ull : kk[9];  break;
      case 10: kk[10] = me ? 0ull : kk[10]; break;
      default: kk[11] = me ? 0ull : kk[11]; break;
    }
  }
}

// ---------------- K3b: gather + nonlinearity + accumulate ----------------
// grid 768 x 128thr; wave = one (b,n); lane = c(0..31) + 32*kh; each half does 8 neighbors.
__global__ __launch_bounds__(128) void k3b_kv(const float* __restrict__ Pb,
    const float* __restrict__ Rb, const int* __restrict__ idxw,
    float* __restrict__ ksum, float* __restrict__ vsum)
{
  int tid = threadIdx.x;
  int w = tid >> 6, lane = tid & 63, kh = lane >> 5, c = lane & 31;
  int p = blockIdx.x * 2 + w;
  int b = p / NPTS, n = p % NPTS;
  const float4* Rp = (const float4*)(Rb + ((size_t)(b * NPTS + n) * 32 + c) * 12);
  float4 r0 = Rp[0], r1 = Rp[1], r2 = Rp[2];
  int ibase = (b * NPTS + n) * 16 + kh * 8;
  int4 ia = *(const int4*)(idxw + ibase);
  int4 ib = *(const int4*)(idxw + ibase + 4);
  int ms[8] = {ia.x, ia.y, ia.z, ia.w, ib.x, ib.y, ib.z, ib.w};
  float ks0 = 0, ks1 = 0, ks2 = 0, vs0 = 0, vs1 = 0, vs2 = 0;
#pragma unroll
  for (int j = 0; j < 8; j++) {
    const float4* Pp = (const float4*)(Pb + ((size_t)(b * NPTS + ms[j]) * 32 + c) * 12);
    float4 p0 = Pp[0], p1 = Pp[1], p2 = Pp[2];
    float kf0 = p0.x + r0.x, kf1 = p0.y + r0.y, kf2 = p0.z + r0.z;
    float kd0 = p0.w + r0.w, kd1 = p1.x + r1.x, kd2 = p1.y + r1.y;
    float vf0 = p1.z + r1.z, vf1 = p1.w + r1.w, vf2 = p2.x + r2.x;
    float vd0 = p2.y + r2.y, vd1 = p2.z + r2.z, vd2 = p2.w + r2.w;
    float dot = kf0 * kd0 + kf1 * kd1 + kf2 * kd2;
    float dsq = kd0 * kd0 + kd1 * kd1 + kd2 * kd2;
    float k0 = kf0, k1 = kf1, k2 = kf2;
    if (dot < 0.f) { float r = 0.8f * dot / (dsq + 1e-6f); k0 -= r * kd0; k1 -= r * kd1; k2 -= r * kd2; }
    float nrm = sqrtf(k0 * k0 + k1 * k1 + k2 * k2);
    float n2 = nrm * nrm;
#pragma unroll
    for (int mm = 1; mm <= 16; mm <<= 1) n2 += __shfl_xor(n2, mm);
    float fac = (nrm / fmaxf(sqrtf(n2), 1e-12f)) / fmaxf(nrm, 1e-12f);
    ks0 = fmaf(k0, fac, ks0); ks1 = fmaf(k1, fac, ks1); ks2 = fmaf(k2, fac, ks2);
    float dotv = vf0 * vd0 + vf1 * vd1 + vf2 * vd2;
    float dsqv = vd0 * vd0 + vd1 * vd1 + vd2 * vd2;
    float v0 = vf0, v1 = vf1, v2 = vf2;
    if (dotv < 0.f) { float r = 0.8f * dotv / (dsqv + 1e-6f); v0 -= r * vd0; v1 -= r * vd1; v2 -= r * vd2; }
    vs0 += v0; vs1 += v1; vs2 += v2;
  }
  ks0 += __shfl_xor(ks0, 32); ks1 += __shfl_xor(ks1, 32); ks2 += __shfl_xor(ks2, 32);
  vs0 += __shfl_xor(vs0, 32); vs1 += __shfl_xor(vs1, 32); vs2 += __shfl_xor(vs2, 32);
  if (kh == 0) {
    int base = ((b * 32 + c) * 3) * NPTS + n;
    ksum[base] = ks0 * SCALE2; ksum[base + NPTS] = ks1 * SCALE2; ksum[base + 2 * NPTS] = ks2 * SCALE2;
    vsum[base] = vs0; vsum[base + NPTS] = vs1; vsum[base + 2 * NPTS] = vs2;
  }
}

// ---------------- K4: attention softmax + output ----------------
// grid = 192 slices * 4 quarters = 768 blocks (3/CU exact), block 192 threads.
// No max subtraction needed: |q|<=1, |s|<=16*scale*log2e=2.36 -> exp2 arg in [-2.4,2.4].
__global__ __launch_bounds__(192) void k4_attn(const float* __restrict__ x,
    const float* __restrict__ qx, const float* __restrict__ ks, const float* __restrict__ vs,
    float* __restrict__ out)
{
  __shared__ float4 s4[192], v4[192];
  int tid = threadIdx.x;
  int sl = blockIdx.x >> 2, quarter = blockIdx.x & 3;
  const float* srow = ks + sl * NPTS;
  const float* vrow = vs + sl * NPTS;
  for (int i = tid; i < NPTS; i += 192) {
    ((float*)s4)[i] = srow[i];
    ((float*)v4)[i] = vrow[i];
  }
  __syncthreads();
  int n = quarter * 192 + tid;
  float q = qx[sl * NPTS + n];
  float num = 0.f, den = 0.f;
#pragma unroll 4
  for (int m4 = 0; m4 < 192; m4++) {
    float4 ss = s4[m4], vv = v4[m4];
    float e0 = __builtin_amdgcn_exp2f(q * ss.x);
    float e1 = __builtin_amdgcn_exp2f(q * ss.y);
    float e2 = __builtin_amdgcn_exp2f(q * ss.z);
    float e3 = __builtin_amdgcn_exp2f(q * ss.w);
    num = fmaf(e0, vv.x, num); den += e0;
    num = fmaf(e1, vv.y, num); den += e1;
    num = fmaf(e2, vv.z, num); den += e2;
    num = fmaf(e3, vv.w, num); den += e3;
  }
  out[sl * NPTS + n] = x[sl * NPTS + n] + num / den;
}

extern "C" void kernel_launch(void* const* d_in, const int* in_sizes, int n_in,
                              void* d_out, int out_size, void* d_ws, size_t ws_size,
                              hipStream_t stream) {
  const float* x   = (const float*)d_in[0];
  const float* y   = (const float*)d_in[1];
  const float* Wqf = (const float*)d_in[2];
  const float* Wqd = (const float*)d_in[3];
  const float* Wkf = (const float*)d_in[4];
  const float* Wkd = (const float*)d_in[5];
  const float* Wvf = (const float*)d_in[6];
  const float* Wvd = (const float*)d_in[7];
  float* out = (float*)d_out;

  float* qx   = (float*)d_ws;            // 147456
  float* ksum = qx + 147456;             // 147456 (pre-scaled by SCALE2)
  float* vsum = ksum + 147456;           // 147456
  int*   idx  = (int*)(vsum + 147456);   // 24576 ints
  float* Pb   = (float*)(idx + 24576);   // 589824
  float* Rb   = Pb + 589824;             // 589824

  k13_pre<<<576, 256, 0, stream>>>(x, y, Wqf, Wqd, Wkf, Wkd, Wvf, Wvd, qx, Pb, Rb);
  k2_knn <<<384, 256, 0, stream>>>(y, idx);
  k3b_kv <<<768, 128, 0, stream>>>(Pb, Rb, idx, ksum, vsum);
  k4_attn<<<768, 192, 0, stream>>>(x, qx, ksum, vsum, out);
}

// Round 5
// 116.884 us; speedup vs baseline: 1.4244x; 1.2044x over previous
//
#include <hip/hip_runtime.h>
#include <hip/hip_bf16.h>

#define NPTS 768
#define SCALE 0.10206207261596575f  // 1/sqrt(96); k4 uses natural-exp Taylor, so no log2e folding

// 1/t! for t=0..12 (natural exp Taylor)
static __device__ const float CFACT[13] = {
  1.0f, 1.0f, 0.5f, 0.16666667f, 0.041666668f, 0.008333334f, 0.0013888889f,
  1.9841270e-4f, 2.4801587e-5f, 2.7557319e-6f, 2.7557319e-7f, 2.5052108e-8f, 2.0876757e-9f
};

// ---------------- KA: fused per-point transforms + kNN ----------------
// bid <  192 : Qx path (x -> qx), 8 points/block, 32 lanes/point
// 192..575   : P/R path (y -> Pb, Rb), 4 points/block, 64 lanes/point
// 576..959   : kNN top-16 path (y -> idx), 4 rows/block
__global__ __launch_bounds__(256) void ka_pre(const float* __restrict__ x,
    const float* __restrict__ y,
    const float* __restrict__ Wqf, const float* __restrict__ Wqd,
    const float* __restrict__ Wkf, const float* __restrict__ Wkd,
    const float* __restrict__ Wvf, const float* __restrict__ Wvd,
    float* __restrict__ qx, float* __restrict__ Pb, float* __restrict__ Rb,
    int* __restrict__ idxout)
{
  __shared__ __align__(16) char smem[34816];
  int tid = threadIdx.x;
  if (blockIdx.x < 192) {
    // ---------- Qx path ----------
    float2* w2 = (float2*)smem;                       // [cin][c] (Wqf, Wqd), 8KB
    float4 (*xs)[32] = (float4(*)[32])(smem + 8192);  // [group][cin], 4KB
    for (int i = tid; i < 1024; i += 256) {
      int cin = i >> 5, c = i & 31;
      w2[i] = make_float2(Wqf[c * 32 + cin], Wqd[c * 32 + cin]);
    }
    int g = tid >> 5, c = tid & 31;
    int p = blockIdx.x * 8 + g;
    int b = p / NPTS, n = p % NPTS;
    for (int t = c; t < 96; t += 32) {
      float v = x[(b * 96 + t) * NPTS + n];
      ((float*)&xs[g][t / 3])[t % 3] = v;
    }
    __syncthreads();
    float pf0 = 0, pf1 = 0, pf2 = 0, pd0 = 0, pd1 = 0, pd2 = 0;
#pragma unroll
    for (int cin = 0; cin < 32; cin++) {
      float2 w = w2[(cin << 5) + c];
      float4 xv = xs[g][cin];
      pf0 = fmaf(w.x, xv.x, pf0); pf1 = fmaf(w.x, xv.y, pf1); pf2 = fmaf(w.x, xv.z, pf2);
      pd0 = fmaf(w.y, xv.x, pd0); pd1 = fmaf(w.y, xv.y, pd1); pd2 = fmaf(w.y, xv.z, pd2);
    }
    float dot = pf0 * pd0 + pf1 * pd1 + pf2 * pd2;
    float dsq = pd0 * pd0 + pd1 * pd1 + pd2 * pd2;
    float q0 = pf0, q1 = pf1, q2 = pf2;
    if (dot < 0.f) {
      float r = 0.8f * dot / (dsq + 1e-6f);
      q0 -= r * pd0; q1 -= r * pd1; q2 -= r * pd2;
    }
    float nrm = sqrtf(q0 * q0 + q1 * q1 + q2 * q2);
    float n2 = nrm * nrm;
#pragma unroll
    for (int m = 1; m <= 16; m <<= 1) n2 += __shfl_xor(n2, m);
    float fac = (nrm / fmaxf(sqrtf(n2), 1e-12f)) / fmaxf(nrm, 1e-12f);
    int base = ((b * 32 + c) * 3) * NPTS + n;
    qx[base] = q0 * fac; qx[base + NPTS] = q1 * fac; qx[base + 2 * NPTS] = q2 * fac;
  } else if (blockIdx.x < 576) {
    // ---------- P/R path ----------
    float4* wLs = (float4*)smem;                        // 1024 entries, 16KB
    float4* wDs = (float4*)(smem + 16384);              // 1024 entries, 16KB
    float4 (*xs)[32] = (float4(*)[32])(smem + 32768);   // [pt][cin], 2KB
    for (int i = tid; i < 1024; i += 256) {
      int cin = i >> 5, c = i & 31;
      float kfL = Wkf[c * 64 + cin], kdL = Wkd[c * 64 + cin];
      float vfL = Wvf[c * 64 + cin], vdL = Wvd[c * 64 + cin];
      wLs[i] = make_float4(kfL, kdL, vfL, vdL);
      wDs[i] = make_float4(Wkf[c * 64 + 32 + cin] - kfL, Wkd[c * 64 + 32 + cin] - kdL,
                           Wvf[c * 64 + 32 + cin] - vfL, Wvd[c * 64 + 32 + cin] - vdL);
    }
    int g = tid >> 6, lane = tid & 63, half = lane >> 5, c = lane & 31;
    int p = (blockIdx.x - 192) * 4 + g;
    int b = p / NPTS, n = p % NPTS;
    for (int t = lane; t < 96; t += 64) {
      float v = y[(b * 96 + t) * NPTS + n];
      ((float*)&xs[g][t / 3])[t % 3] = v;
    }
    __syncthreads();
    const float4* wsel = half ? wDs : wLs;
    float kf0 = 0, kf1 = 0, kf2 = 0, kd0 = 0, kd1 = 0, kd2 = 0;
    float vf0 = 0, vf1 = 0, vf2 = 0, vd0 = 0, vd1 = 0, vd2 = 0;
#pragma unroll 8
    for (int cin = 0; cin < 32; cin++) {
      float4 wv = wsel[(cin << 5) + c];
      float4 xv = xs[g][cin];
      kf0 = fmaf(wv.x, xv.x, kf0); kf1 = fmaf(wv.x, xv.y, kf1); kf2 = fmaf(wv.x, xv.z, kf2);
      kd0 = fmaf(wv.y, xv.x, kd0); kd1 = fmaf(wv.y, xv.y, kd1); kd2 = fmaf(wv.y, xv.z, kd2);
      vf0 = fmaf(wv.z, xv.x, vf0); vf1 = fmaf(wv.z, xv.y, vf1); vf2 = fmaf(wv.z, xv.z, vf2);
      vd0 = fmaf(wv.w, xv.x, vd0); vd1 = fmaf(wv.w, xv.y, vd1); vd2 = fmaf(wv.w, xv.z, vd2);
    }
    float* dst = half ? Rb : Pb;
    size_t base = ((size_t)(b * NPTS + n) * 32 + c) * 12;
    float4* Dp = (float4*)(dst + base);
    Dp[0] = make_float4(kf0, kf1, kf2, kd0);
    Dp[1] = make_float4(kd1, kd2, vf0, vf1);
    Dp[2] = make_float4(vf2, vd0, vd1, vd2);
  } else {
    // ---------- kNN path ----------
    // Ranking within a row n needs only 2*inner - sq[m]  (sq[n] is a per-row constant shift).
    float4 (*as4)[24] = (float4(*)[24])smem;                 // [j][f4], 1536B
    unsigned int (*kd)[NPTS] = (unsigned int(*)[NPTS])(smem + 1536);  // [j][m], 12KB
    int kb = blockIdx.x - 576;
    int b = kb / 192;
    int n0 = (kb % 192) * 4;
    const float* yb = y + b * 96 * NPTS;
    for (int i = tid; i < 384; i += 256) {
      int j = i / 96, f = i % 96;
      ((float*)as4)[j * 96 + f] = yb[f * NPTS + n0 + j];
    }
    __syncthreads();
    float in[12];                       // [j][r]
    float sqm[3] = {0.f, 0.f, 0.f};
#pragma unroll
    for (int t = 0; t < 12; t++) in[t] = 0.f;
#pragma unroll 4
    for (int f4 = 0; f4 < 24; f4++) {
      float4 a0 = as4[0][f4], a1 = as4[1][f4], a2 = as4[2][f4], a3 = as4[3][f4];
#pragma unroll
      for (int r = 0; r < 3; r++) {
        int m = r * 256 + tid;
        const float* col = yb + (f4 * 4) * NPTS + m;
        float b0 = col[0], b1 = col[NPTS], b2 = col[2 * NPTS], b3 = col[3 * NPTS];
        sqm[r] = fmaf(b0, b0, fmaf(b1, b1, fmaf(b2, b2, fmaf(b3, b3, sqm[r]))));
        in[0 + r] = fmaf(a0.x, b0, fmaf(a0.y, b1, fmaf(a0.z, b2, fmaf(a0.w, b3, in[0 + r]))));
        in[3 + r] = fmaf(a1.x, b0, fmaf(a1.y, b1, fmaf(a1.z, b2, fmaf(a1.w, b3, in[3 + r]))));
        in[6 + r] = fmaf(a2.x, b0, fmaf(a2.y, b1, fmaf(a2.z, b2, fmaf(a2.w, b3, in[6 + r]))));
        in[9 + r] = fmaf(a3.x, b0, fmaf(a3.y, b1, fmaf(a3.z, b2, fmaf(a3.w, b3, in[9 + r]))));
      }
    }
#pragma unroll
    for (int j = 0; j < 4; j++) {
#pragma unroll
      for (int r = 0; r < 3; r++) {
        int m = r * 256 + tid;
        float v = 2.f * in[j * 3 + r] - sqm[r];
        unsigned int u = __float_as_uint(v);
        u = (u & 0x80000000u) ? ~u : (u | 0x80000000u);   // monotone map (exact)
        kd[j][m] = u;
      }
    }
    __syncthreads();
    int w = tid >> 6, lane = tid & 63;
    unsigned long long kk[12];
#pragma unroll
    for (int j = 0; j < 12; j++) {
      int m = lane + 64 * j;
      kk[j] = ((unsigned long long)kd[w][m] << 10) | (unsigned)(1023 - m);
    }
    int outbase = (b * NPTS + n0 + w) * 16;
    for (int it = 0; it < 16; it++) {
      unsigned long long a0 = kk[0] > kk[1] ? kk[0] : kk[1];
      unsigned long long a1 = kk[2] > kk[3] ? kk[2] : kk[3];
      unsigned long long a2 = kk[4] > kk[5] ? kk[4] : kk[5];
      unsigned long long a3 = kk[6] > kk[7] ? kk[6] : kk[7];
      unsigned long long a4 = kk[8] > kk[9] ? kk[8] : kk[9];
      unsigned long long a5 = kk[10] > kk[11] ? kk[10] : kk[11];
      unsigned long long b0 = a0 > a1 ? a0 : a1;
      unsigned long long b1 = a2 > a3 ? a2 : a3;
      unsigned long long b2 = a4 > a5 ? a4 : a5;
      unsigned long long best = b0 > b1 ? b0 : b1;
      best = best > b2 ? best : b2;
#pragma unroll
      for (int off = 1; off <= 32; off <<= 1) {
        unsigned long long o = __shfl_xor(best, off);
        best = o > best ? o : best;
      }
      int wm = 1023 - (int)(best & 1023u);
      if (lane == 0) idxout[outbase + it] = wm;
      int jj = wm >> 6;                 // wave-uniform
      bool me = (lane == (wm & 63));
      switch (jj) {
        case 0:  kk[0]  = me ? 0ull : kk[0];  break;
        case 1:  kk[1]  = me ? 0ull : kk[1];  break;
        case 2:  kk[2]  = me ? 0ull : kk[2];  break;
        case 3:  kk[3]  = me ? 0ull : kk[3];  break;
        case 4:  kk[4]  = me ? 0ull : kk[4];  break;
        case 5:  kk[5]  = me ? 0ull : kk[5];  break;
        case 6:  kk[6]  = me ? 0ull : kk[6];  break;
        case 7:  kk[7]  = me ? 0ull : kk[7];  break;
        case 8:  kk[8]  = me ? 0ull : kk[8];  break;
        case 9:  kk[9]  = me ? 0ull : kk[9];  break;
        case 10: kk[10] = me ? 0ull : kk[10]; break;
        default: kk[11] = me ? 0ull : kk[11]; break;
      }
    }
  }
}

// ---------------- KB: gather + nonlinearity + accumulate ----------------
// grid 768 x 128thr; wave = one (b,n); lane = c(0..31) + 32*kh; each half does 8 neighbors.
__global__ __launch_bounds__(128) void kb_kv(const float* __restrict__ Pb,
    const float* __restrict__ Rb, const int* __restrict__ idxw,
    float* __restrict__ ksum, float* __restrict__ vsum)
{
  int tid = threadIdx.x;
  int w = tid >> 6, lane = tid & 63, kh = lane >> 5, c = lane & 31;
  int p = blockIdx.x * 2 + w;
  int b = p / NPTS, n = p % NPTS;
  const float4* Rp = (const float4*)(Rb + ((size_t)(b * NPTS + n) * 32 + c) * 12);
  float4 r0 = Rp[0], r1 = Rp[1], r2 = Rp[2];
  int ibase = (b * NPTS + n) * 16 + kh * 8;
  int4 ia = *(const int4*)(idxw + ibase);
  int4 ib = *(const int4*)(idxw + ibase + 4);
  int ms[8] = {ia.x, ia.y, ia.z, ia.w, ib.x, ib.y, ib.z, ib.w};
  float ks0 = 0, ks1 = 0, ks2 = 0, vs0 = 0, vs1 = 0, vs2 = 0;
#pragma unroll
  for (int j = 0; j < 8; j++) {
    const float4* Pp = (const float4*)(Pb + ((size_t)(b * NPTS + ms[j]) * 32 + c) * 12);
    float4 p0 = Pp[0], p1 = Pp[1], p2 = Pp[2];
    float kf0 = p0.x + r0.x, kf1 = p0.y + r0.y, kf2 = p0.z + r0.z;
    float kd0 = p0.w + r0.w, kd1 = p1.x + r1.x, kd2 = p1.y + r1.y;
    float vf0 = p1.z + r1.z, vf1 = p1.w + r1.w, vf2 = p2.x + r2.x;
    float vd0 = p2.y + r2.y, vd1 = p2.z + r2.z, vd2 = p2.w + r2.w;
    float dot = kf0 * kd0 + kf1 * kd1 + kf2 * kd2;
    float dsq = kd0 * kd0 + kd1 * kd1 + kd2 * kd2;
    float k0 = kf0, k1 = kf1, k2 = kf2;
    if (dot < 0.f) { float r = 0.8f * dot / (dsq + 1e-6f); k0 -= r * kd0; k1 -= r * kd1; k2 -= r * kd2; }
    float nrm = sqrtf(k0 * k0 + k1 * k1 + k2 * k2);
    float n2 = nrm * nrm;
#pragma unroll
    for (int mm = 1; mm <= 16; mm <<= 1) n2 += __shfl_xor(n2, mm);
    float fac = (nrm / fmaxf(sqrtf(n2), 1e-12f)) / fmaxf(nrm, 1e-12f);
    ks0 = fmaf(k0, fac, ks0); ks1 = fmaf(k1, fac, ks1); ks2 = fmaf(k2, fac, ks2);
    float dotv = vf0 * vd0 + vf1 * vd1 + vf2 * vd2;
    float dsqv = vd0 * vd0 + vd1 * vd1 + vd2 * vd2;
    float v0 = vf0, v1 = vf1, v2 = vf2;
    if (dotv < 0.f) { float r = 0.8f * dotv / (dsqv + 1e-6f); v0 -= r * vd0; v1 -= r * vd1; v2 -= r * vd2; }
    vs0 += v0; vs1 += v1; vs2 += v2;
  }
  ks0 += __shfl_xor(ks0, 32); ks1 += __shfl_xor(ks1, 32); ks2 += __shfl_xor(ks2, 32);
  vs0 += __shfl_xor(vs0, 32); vs1 += __shfl_xor(vs1, 32); vs2 += __shfl_xor(vs2, 32);
  if (kh == 0) {
    int base = ((b * 32 + c) * 3) * NPTS + n;
    ksum[base] = ks0 * SCALE; ksum[base + NPTS] = ks1 * SCALE; ksum[base + 2 * NPTS] = ks2 * SCALE;
    vsum[base] = vs0; vsum[base + NPTS] = vs1; vsum[base + 2 * NPTS] = vs2;
  }
}

// ---------------- KC: attention via Taylor power-moments ----------------
// |q| <= 1, |s| <= 16/sqrt(96) = 1.633  ->  exp(q*s) Taylor deg-12, remainder < 1e-6.
// Per slice: P_t = sum_m s^t, Q_t = sum_m s^t v  (t<=12); per query: 24-fma Horner.
// One block per slice (192 blocks x 256 threads).
__global__ __launch_bounds__(256) void kc_attn(const float* __restrict__ x,
    const float* __restrict__ qx, const float* __restrict__ ks, const float* __restrict__ vs,
    float* __restrict__ out)
{
  __shared__ float red[4][25];
  __shared__ float AB[26];    // AB[0..12] = c_t*P_t (den coeffs), AB[13..25] = c_t*Q_t (num coeffs)
  int tid = threadIdx.x;
  int sl = blockIdx.x;
  const float* srow = ks + sl * NPTS;
  const float* vrow = vs + sl * NPTS;
  float P[12], Q[13];   // P[t] = sum s^{t+1};  Q[0] = sum v, Q[t] = sum s^t v
#pragma unroll
  for (int t = 0; t < 12; t++) P[t] = 0.f;
#pragma unroll
  for (int t = 0; t < 13; t++) Q[t] = 0.f;
  for (int m = tid; m < NPTS; m += 256) {
    float s = srow[m], v = vrow[m];
    Q[0] += v;
    float pw = s;
#pragma unroll
    for (int t = 0; t < 12; t++) {
      P[t] += pw;
      Q[t + 1] = fmaf(pw, v, Q[t + 1]);
      pw *= s;
    }
  }
#pragma unroll
  for (int off = 1; off <= 32; off <<= 1) {
#pragma unroll
    for (int t = 0; t < 12; t++) P[t] += __shfl_xor(P[t], off);
#pragma unroll
    for (int t = 0; t < 13; t++) Q[t] += __shfl_xor(Q[t], off);
  }
  int lane = tid & 63, wid = tid >> 6;
  if (lane == 0) {
#pragma unroll
    for (int t = 0; t < 12; t++) red[wid][t] = P[t];
#pragma unroll
    for (int t = 0; t < 13; t++) red[wid][12 + t] = Q[t];
  }
  __syncthreads();
  if (tid < 25) {
    float sm = red[0][tid] + red[1][tid] + red[2][tid] + red[3][tid];
    if (tid < 12) AB[1 + tid] = CFACT[1 + tid] * sm;          // A_t = P_t/t!, t=1..12
    else          AB[13 + (tid - 12)] = CFACT[tid - 12] * sm; // B_t = Q_t/t!, t=0..12
  }
  if (tid == 25) AB[0] = (float)NPTS;                          // A_0 = sum s^0
  __syncthreads();
#pragma unroll
  for (int nn = 0; nn < 3; nn++) {
    int n = nn * 256 + tid;
    float q = qx[sl * NPTS + n];
    float den = AB[12], num = AB[25];
#pragma unroll
    for (int t = 11; t >= 0; t--) {
      den = fmaf(den, q, AB[t]);
      num = fmaf(num, q, AB[13 + t]);
    }
    out[sl * NPTS + n] = x[sl * NPTS + n] + num / den;
  }
}

extern "C" void kernel_launch(void* const* d_in, const int* in_sizes, int n_in,
                              void* d_out, int out_size, void* d_ws, size_t ws_size,
                              hipStream_t stream) {
  const float* x   = (const float*)d_in[0];
  const float* y   = (const float*)d_in[1];
  const float* Wqf = (const float*)d_in[2];
  const float* Wqd = (const float*)d_in[3];
  const float* Wkf = (const float*)d_in[4];
  const float* Wkd = (const float*)d_in[5];
  const float* Wvf = (const float*)d_in[6];
  const float* Wvd = (const float*)d_in[7];
  float* out = (float*)d_out;

  float* qx   = (float*)d_ws;            // 147456
  float* ksum = qx + 147456;             // 147456 (pre-scaled by 1/sqrt(96))
  float* vsum = ksum + 147456;           // 147456
  int*   idx  = (int*)(vsum + 147456);   // 24576 ints
  float* Pb   = (float*)(idx + 24576);   // 589824
  float* Rb   = Pb + 589824;             // 589824

  ka_pre <<<960, 256, 0, stream>>>(x, y, Wqf, Wqd, Wkf, Wkd, Wvf, Wvd, qx, Pb, Rb, idx);
  kb_kv  <<<768, 128, 0, stream>>>(Pb, Rb, idx, ksum, vsum);
  kc_attn<<<192, 256, 0, stream>>>(x, qx, ksum, vsum, out);
}

// Round 7
// 116.161 us; speedup vs baseline: 1.4333x; 1.0062x over previous
//
#include <hip/hip_runtime.h>
#include <hip/hip_bf16.h>

#define NPTS 768
#define SCALE 0.10206207261596575f  // 1/sqrt(96); attention uses natural-exp Taylor

// 1/t! for t=0..12 (natural exp Taylor)
static __device__ const float CFACT[13] = {
  1.0f, 1.0f, 0.5f, 0.16666667f, 0.041666668f, 0.008333334f, 0.0013888889f,
  1.9841270e-4f, 2.4801587e-5f, 2.7557319e-6f, 2.7557319e-7f, 2.5052108e-8f, 2.0876757e-9f
};

// ---------------- KA: fused per-point transforms + kNN ----------------
// bid <  192 : Qx path (x -> qx), 8 points/block, 32 lanes/point
// 192..575   : P/R path (y -> Pb, Rb), 4 points/block, 64 lanes/point
// 576..959   : kNN top-16 path (y -> idx), 4 rows/block
__global__ __launch_bounds__(256) void ka_pre(const float* __restrict__ x,
    const float* __restrict__ y,
    const float* __restrict__ Wqf, const float* __restrict__ Wqd,
    const float* __restrict__ Wkf, const float* __restrict__ Wkd,
    const float* __restrict__ Wvf, const float* __restrict__ Wvd,
    float* __restrict__ qx, float* __restrict__ Pb, float* __restrict__ Rb,
    int* __restrict__ idxout)
{
  __shared__ __align__(16) char smem[34816];
  int tid = threadIdx.x;
  if (blockIdx.x < 192) {
    // ---------- Qx path ----------
    float2* w2 = (float2*)smem;                       // [cin][c] (Wqf, Wqd), 8KB
    float4 (*xs)[32] = (float4(*)[32])(smem + 8192);  // [group][cin], 4KB
    for (int i = tid; i < 1024; i += 256) {
      int cin = i >> 5, c = i & 31;
      w2[i] = make_float2(Wqf[c * 32 + cin], Wqd[c * 32 + cin]);
    }
    int g = tid >> 5, c = tid & 31;
    int p = blockIdx.x * 8 + g;
    int b = p / NPTS, n = p % NPTS;
    for (int t = c; t < 96; t += 32) {
      float v = x[(b * 96 + t) * NPTS + n];
      ((float*)&xs[g][t / 3])[t % 3] = v;
    }
    __syncthreads();
    float pf0 = 0, pf1 = 0, pf2 = 0, pd0 = 0, pd1 = 0, pd2 = 0;
#pragma unroll
    for (int cin = 0; cin < 32; cin++) {
      float2 w = w2[(cin << 5) + c];
      float4 xv = xs[g][cin];
      pf0 = fmaf(w.x, xv.x, pf0); pf1 = fmaf(w.x, xv.y, pf1); pf2 = fmaf(w.x, xv.z, pf2);
      pd0 = fmaf(w.y, xv.x, pd0); pd1 = fmaf(w.y, xv.y, pd1); pd2 = fmaf(w.y, xv.z, pd2);
    }
    float dot = pf0 * pd0 + pf1 * pd1 + pf2 * pd2;
    float dsq = pd0 * pd0 + pd1 * pd1 + pd2 * pd2;
    float q0 = pf0, q1 = pf1, q2 = pf2;
    if (dot < 0.f) {
      float r = 0.8f * dot / (dsq + 1e-6f);
      q0 -= r * pd0; q1 -= r * pd1; q2 -= r * pd2;
    }
    float nrm = sqrtf(q0 * q0 + q1 * q1 + q2 * q2);
    float n2 = nrm * nrm;
#pragma unroll
    for (int m = 1; m <= 16; m <<= 1) n2 += __shfl_xor(n2, m);
    float fac = (nrm / fmaxf(sqrtf(n2), 1e-12f)) / fmaxf(nrm, 1e-12f);
    int base = ((b * 32 + c) * 3) * NPTS + n;
    qx[base] = q0 * fac; qx[base + NPTS] = q1 * fac; qx[base + 2 * NPTS] = q2 * fac;
  } else if (blockIdx.x < 576) {
    // ---------- P/R path ----------
    float4* wLs = (float4*)smem;                        // 1024 entries, 16KB
    float4* wDs = (float4*)(smem + 16384);              // 1024 entries, 16KB
    float4 (*xs)[32] = (float4(*)[32])(smem + 32768);   // [pt][cin], 2KB
    for (int i = tid; i < 1024; i += 256) {
      int cin = i >> 5, c = i & 31;
      float kfL = Wkf[c * 64 + cin], kdL = Wkd[c * 64 + cin];
      float vfL = Wvf[c * 64 + cin], vdL = Wvd[c * 64 + cin];
      wLs[i] = make_float4(kfL, kdL, vfL, vdL);
      wDs[i] = make_float4(Wkf[c * 64 + 32 + cin] - kfL, Wkd[c * 64 + 32 + cin] - kdL,
                           Wvf[c * 64 + 32 + cin] - vfL, Wvd[c * 64 + 32 + cin] - vdL);
    }
    int g = tid >> 6, lane = tid & 63, half = lane >> 5, c = lane & 31;
    int p = (blockIdx.x - 192) * 4 + g;
    int b = p / NPTS, n = p % NPTS;
    for (int t = lane; t < 96; t += 64) {
      float v = y[(b * 96 + t) * NPTS + n];
      ((float*)&xs[g][t / 3])[t % 3] = v;
    }
    __syncthreads();
    const float4* wsel = half ? wDs : wLs;
    float kf0 = 0, kf1 = 0, kf2 = 0, kd0 = 0, kd1 = 0, kd2 = 0;
    float vf0 = 0, vf1 = 0, vf2 = 0, vd0 = 0, vd1 = 0, vd2 = 0;
#pragma unroll 8
    for (int cin = 0; cin < 32; cin++) {
      float4 wv = wsel[(cin << 5) + c];
      float4 xv = xs[g][cin];
      kf0 = fmaf(wv.x, xv.x, kf0); kf1 = fmaf(wv.x, xv.y, kf1); kf2 = fmaf(wv.x, xv.z, kf2);
      kd0 = fmaf(wv.y, xv.x, kd0); kd1 = fmaf(wv.y, xv.y, kd1); kd2 = fmaf(wv.y, xv.z, kd2);
      vf0 = fmaf(wv.z, xv.x, vf0); vf1 = fmaf(wv.z, xv.y, vf1); vf2 = fmaf(wv.z, xv.z, vf2);
      vd0 = fmaf(wv.w, xv.x, vd0); vd1 = fmaf(wv.w, xv.y, vd1); vd2 = fmaf(wv.w, xv.z, vd2);
    }
    float* dst = half ? Rb : Pb;
    size_t base = ((size_t)(b * NPTS + n) * 32 + c) * 12;
    float4* Dp = (float4*)(dst + base);
    Dp[0] = make_float4(kf0, kf1, kf2, kd0);
    Dp[1] = make_float4(kd1, kd2, vf0, vf1);
    Dp[2] = make_float4(vf2, vd0, vd1, vd2);
  } else {
    // ---------- kNN path ----------
    // Ranking within a row n needs only 2*inner - sq[m]  (sq[n] is a per-row constant shift).
    float4 (*as4)[24] = (float4(*)[24])smem;                 // [j][f4], 1536B
    unsigned int (*kd)[NPTS] = (unsigned int(*)[NPTS])(smem + 1536);  // [j][m], 12KB
    int kb = blockIdx.x - 576;
    int b = kb / 192;
    int n0 = (kb % 192) * 4;
    const float* yb = y + b * 96 * NPTS;
    for (int i = tid; i < 384; i += 256) {
      int j = i / 96, f = i % 96;
      ((float*)as4)[j * 96 + f] = yb[f * NPTS + n0 + j];
    }
    __syncthreads();
    float in[12];                       // [j][r]
    float sqm[3] = {0.f, 0.f, 0.f};
#pragma unroll
    for (int t = 0; t < 12; t++) in[t] = 0.f;
#pragma unroll 4
    for (int f4 = 0; f4 < 24; f4++) {
      float4 a0 = as4[0][f4], a1 = as4[1][f4], a2 = as4[2][f4], a3 = as4[3][f4];
#pragma unroll
      for (int r = 0; r < 3; r++) {
        int m = r * 256 + tid;
        const float* col = yb + (f4 * 4) * NPTS + m;
        float b0 = col[0], b1 = col[NPTS], b2 = col[2 * NPTS], b3 = col[3 * NPTS];
        sqm[r] = fmaf(b0, b0, fmaf(b1, b1, fmaf(b2, b2, fmaf(b3, b3, sqm[r]))));
        in[0 + r] = fmaf(a0.x, b0, fmaf(a0.y, b1, fmaf(a0.z, b2, fmaf(a0.w, b3, in[0 + r]))));
        in[3 + r] = fmaf(a1.x, b0, fmaf(a1.y, b1, fmaf(a1.z, b2, fmaf(a1.w, b3, in[3 + r]))));
        in[6 + r] = fmaf(a2.x, b0, fmaf(a2.y, b1, fmaf(a2.z, b2, fmaf(a2.w, b3, in[6 + r]))));
        in[9 + r] = fmaf(a3.x, b0, fmaf(a3.y, b1, fmaf(a3.z, b2, fmaf(a3.w, b3, in[9 + r]))));
      }
    }
#pragma unroll
    for (int j = 0; j < 4; j++) {
#pragma unroll
      for (int r = 0; r < 3; r++) {
        int m = r * 256 + tid;
        float v = 2.f * in[j * 3 + r] - sqm[r];
        unsigned int u = __float_as_uint(v);
        u = (u & 0x80000000u) ? ~u : (u | 0x80000000u);   // monotone map (exact)
        kd[j][m] = u;
      }
    }
    __syncthreads();
    int w = tid >> 6, lane = tid & 63;
    unsigned long long kk[12];
#pragma unroll
    for (int j = 0; j < 12; j++) {
      int m = lane + 64 * j;
      kk[j] = ((unsigned long long)kd[w][m] << 10) | (unsigned)(1023 - m);
    }
    int outbase = (b * NPTS + n0 + w) * 16;
    for (int it = 0; it < 16; it++) {
      unsigned long long a0 = kk[0] > kk[1] ? kk[0] : kk[1];
      unsigned long long a1 = kk[2] > kk[3] ? kk[2] : kk[3];
      unsigned long long a2 = kk[4] > kk[5] ? kk[4] : kk[5];
      unsigned long long a3 = kk[6] > kk[7] ? kk[6] : kk[7];
      unsigned long long a4 = kk[8] > kk[9] ? kk[8] : kk[9];
      unsigned long long a5 = kk[10] > kk[11] ? kk[10] : kk[11];
      unsigned long long b0 = a0 > a1 ? a0 : a1;
      unsigned long long b1 = a2 > a3 ? a2 : a3;
      unsigned long long b2 = a4 > a5 ? a4 : a5;
      unsigned long long best = b0 > b1 ? b0 : b1;
      best = best > b2 ? best : b2;
#pragma unroll
      for (int off = 1; off <= 32; off <<= 1) {
        unsigned long long o = __shfl_xor(best, off);
        best = o > best ? o : best;
      }
      int wm = 1023 - (int)(best & 1023u);
      if (lane == 0) idxout[outbase + it] = wm;
      int jj = wm >> 6;                 // wave-uniform
      bool me = (lane == (wm & 63));
      switch (jj) {
        case 0:  kk[0]  = me ? 0ull : kk[0];  break;
        case 1:  kk[1]  = me ? 0ull : kk[1];  break;
        case 2:  kk[2]  = me ? 0ull : kk[2];  break;
        case 3:  kk[3]  = me ? 0ull : kk[3];  break;
        case 4:  kk[4]  = me ? 0ull : kk[4];  break;
        case 5:  kk[5]  = me ? 0ull : kk[5];  break;
        case 6:  kk[6]  = me ? 0ull : kk[6];  break;
        case 7:  kk[7]  = me ? 0ull : kk[7];  break;
        case 8:  kk[8]  = me ? 0ull : kk[8];  break;
        case 9:  kk[9]  = me ? 0ull : kk[9];  break;
        case 10: kk[10] = me ? 0ull : kk[10]; break;
        default: kk[11] = me ? 0ull : kk[11]; break;
      }
    }
  }
}

// ---------------- KB: gather + nonlinearity + accumulate ----------------
// grid 768 x 128thr; wave = one (b,n); lane = c(0..31) + 32*kh; each half does 8 neighbors.
__global__ __launch_bounds__(128) void kb_kv(const float* __restrict__ Pb,
    const float* __restrict__ Rb, const int* __restrict__ idxw,
    float* __restrict__ ksum, float* __restrict__ vsum)
{
  int tid = threadIdx.x;
  int w = tid >> 6, lane = tid & 63, kh = lane >> 5, c = lane & 31;
  int p = blockIdx.x * 2 + w;
  int b = p / NPTS, n = p % NPTS;
  const float4* Rp = (const float4*)(Rb + ((size_t)(b * NPTS + n) * 32 + c) * 12);
  float4 r0 = Rp[0], r1 = Rp[1], r2 = Rp[2];
  int ibase = (b * NPTS + n) * 16 + kh * 8;
  int4 ia = *(const int4*)(idxw + ibase);
  int4 ib = *(const int4*)(idxw + ibase + 4);
  int ms[8] = {ia.x, ia.y, ia.z, ia.w, ib.x, ib.y, ib.z, ib.w};
  float ks0 = 0, ks1 = 0, ks2 = 0, vs0 = 0, vs1 = 0, vs2 = 0;
#pragma unroll
  for (int j = 0; j < 8; j++) {
    const float4* Pp = (const float4*)(Pb + ((size_t)(b * NPTS + ms[j]) * 32 + c) * 12);
    float4 p0 = Pp[0], p1 = Pp[1], p2 = Pp[2];
    float kf0 = p0.x + r0.x, kf1 = p0.y + r0.y, kf2 = p0.z + r0.z;
    float kd0 = p0.w + r0.w, kd1 = p1.x + r1.x, kd2 = p1.y + r1.y;
    float vf0 = p1.z + r1.z, vf1 = p1.w + r1.w, vf2 = p2.x + r2.x;
    float vd0 = p2.y + r2.y, vd1 = p2.z + r2.z, vd2 = p2.w + r2.w;
    float dot = kf0 * kd0 + kf1 * kd1 + kf2 * kd2;
    float dsq = kd0 * kd0 + kd1 * kd1 + kd2 * kd2;
    float k0 = kf0, k1 = kf1, k2 = kf2;
    if (dot < 0.f) { float r = 0.8f * dot / (dsq + 1e-6f); k0 -= r * kd0; k1 -= r * kd1; k2 -= r * kd2; }
    float nrm = sqrtf(k0 * k0 + k1 * k1 + k2 * k2);
    float n2 = nrm * nrm;
#pragma unroll
    for (int mm = 1; mm <= 16; mm <<= 1) n2 += __shfl_xor(n2, mm);
    float fac = (nrm / fmaxf(sqrtf(n2), 1e-12f)) / fmaxf(nrm, 1e-12f);
    ks0 = fmaf(k0, fac, ks0); ks1 = fmaf(k1, fac, ks1); ks2 = fmaf(k2, fac, ks2);
    float dotv = vf0 * vd0 + vf1 * vd1 + vf2 * vd2;
    float dsqv = vd0 * vd0 + vd1 * vd1 + vd2 * vd2;
    float v0 = vf0, v1 = vf1, v2 = vf2;
    if (dotv < 0.f) { float r = 0.8f * dotv / (dsqv + 1e-6f); v0 -= r * vd0; v1 -= r * vd1; v2 -= r * vd2; }
    vs0 += v0; vs1 += v1; vs2 += v2;
  }
  ks0 += __shfl_xor(ks0, 32); ks1 += __shfl_xor(ks1, 32); ks2 += __shfl_xor(ks2, 32);
  vs0 += __shfl_xor(vs0, 32); vs1 += __shfl_xor(vs1, 32); vs2 += __shfl_xor(vs2, 32);
  if (kh == 0) {
    int base = ((b * 32 + c) * 3) * NPTS + n;
    ksum[base] = ks0 * SCALE; ksum[base + NPTS] = ks1 * SCALE; ksum[base + 2 * NPTS] = ks2 * SCALE;
    vsum[base] = vs0; vsum[base + NPTS] = vs1; vsum[base + 2 * NPTS] = vs2;
  }
}

// ---------------- KC: attention via Taylor power-moments ----------------
// |q| <= 1, |s| <= 16/sqrt(96) = 1.633  ->  exp(q*s) Taylor deg-12, remainder < 1e-6.
// Per slice: P_t = sum_m s^t, Q_t = sum_m s^t v  (t<=12); per query: 24-fma Horner.
// One block per slice (192 blocks x 256 threads).
__global__ __launch_bounds__(256) void kc_attn(const float* __restrict__ x,
    const float* __restrict__ qx, const float* __restrict__ ks, const float* __restrict__ vs,
    float* __restrict__ out)
{
  __shared__ float red[4][25];
  __shared__ float AB[26];    // AB[0..12] = c_t*P_t (den coeffs), AB[13..25] = c_t*Q_t (num coeffs)
  int tid = threadIdx.x;
  int sl = blockIdx.x;
  const float* srow = ks + sl * NPTS;
  const float* vrow = vs + sl * NPTS;
  float P[12], Q[13];   // P[t] = sum s^{t+1};  Q[0] = sum v, Q[t] = sum s^t v
#pragma unroll
  for (int t = 0; t < 12; t++) P[t] = 0.f;
#pragma unroll
  for (int t = 0; t < 13; t++) Q[t] = 0.f;
  for (int m = tid; m < NPTS; m += 256) {
    float s = srow[m], v = vrow[m];
    Q[0] += v;
    float pw = s;
#pragma unroll
    for (int t = 0; t < 12; t++) {
      P[t] += pw;
      Q[t + 1] = fmaf(pw, v, Q[t + 1]);
      pw *= s;
    }
  }
#pragma unroll
  for (int off = 1; off <= 32; off <<= 1) {
#pragma unroll
    for (int t = 0; t < 12; t++) P[t] += __shfl_xor(P[t], off);
#pragma unroll
    for (int t = 0; t < 13; t++) Q[t] += __shfl_xor(Q[t], off);
  }
  int lane = tid & 63, wid = tid >> 6;
  if (lane == 0) {
#pragma unroll
    for (int t = 0; t < 12; t++) red[wid][t] = P[t];
#pragma unroll
    for (int t = 0; t < 13; t++) red[wid][12 + t] = Q[t];
  }
  __syncthreads();
  if (tid < 25) {
    float sm = red[0][tid] + red[1][tid] + red[2][tid] + red[3][tid];
    if (tid < 12) AB[1 + tid] = CFACT[1 + tid] * sm;          // A_t = P_t/t!, t=1..12
    else          AB[13 + (tid - 12)] = CFACT[tid - 12] * sm; // B_t = Q_t/t!, t=0..12
  }
  if (tid == 25) AB[0] = (float)NPTS;                          // A_0 = sum s^0
  __syncthreads();
#pragma unroll
  for (int nn = 0; nn < 3; nn++) {
    int n = nn * 256 + tid;
    float q = qx[sl * NPTS + n];
    float den = AB[12], num = AB[25];
#pragma unroll
    for (int t = 11; t >= 0; t--) {
      den = fmaf(den, q, AB[t]);
      num = fmaf(num, q, AB[13 + t]);
    }
    out[sl * NPTS + n] = x[sl * NPTS + n] + num / den;
  }
}

extern "C" void kernel_launch(void* const* d_in, const int* in_sizes, int n_in,
                              void* d_out, int out_size, void* d_ws, size_t ws_size,
                              hipStream_t stream) {
  const float* x   = (const float*)d_in[0];
  const float* y   = (const float*)d_in[1];
  const float* Wqf = (const float*)d_in[2];
  const float* Wqd = (const float*)d_in[3];
  const float* Wkf = (const float*)d_in[4];
  const float* Wkd = (const float*)d_in[5];
  const float* Wvf = (const float*)d_in[6];
  const float* Wvd = (const float*)d_in[7];
  float* out = (float*)d_out;

  float* qx   = (float*)d_ws;            // 147456
  float* ksum = qx + 147456;             // 147456 (pre-scaled by 1/sqrt(96))
  float* vsum = ksum + 147456;           // 147456
  int*   idx  = (int*)(vsum + 147456);   // 24576 ints
  float* Pb   = (float*)(idx + 24576);   // 589824
  float* Rb   = Pb + 589824;             // 589824

  ka_pre <<<960, 256, 0, stream>>>(x, y, Wqf, Wqd, Wkf, Wkd, Wvf, Wvd, qx, Pb, Rb, idx);
  kb_kv  <<<768, 128, 0, stream>>>(Pb, Rb, idx, ksum, vsum);
  kc_attn<<<192, 256, 0, stream>>>(x, qx, ksum, vsum, out);
}